// Round 2
// baseline (396.029 us; speedup 1.0000x reference)
//
#include <hip/hip_runtime.h>

#define WORKER_NUM 2000
#define TASK_NUM   5000
#define EDGE_TYPE  10
#define INPUT_DIM  64

// Total output elements: 2000 * 5000 * 10 = 100,000,000 fp32 (400 MB)
#define TAU_ELEMS  (TASK_NUM * EDGE_TYPE)       // 50,000
#define TOTAL4     (WORKER_NUM * TAU_ELEMS / 4) // 25,000,000 float4
#define TAU4       (TAU_ELEMS / 4)              // 12,500

// ---------------------------------------------------------------------------
// Prep: blocks [0,500) -> per-worker (base, slope) in log2 space, one wave
// per worker (coalesced row load + shfl_xor reduce).
// blocks [500, ...) -> pack tau (strided slice of inputs) into a dense buffer.
// ---------------------------------------------------------------------------
__global__ __launch_bounds__(256) void prep_kernel(
    const float* __restrict__ inputs,
    const float* __restrict__ W,
    const float* __restrict__ b,
    float2* __restrict__ params,   // [WORKER_NUM] {base=log2(p2), slope=log2(p1)-log2(p2)}
    float* __restrict__ tau)       // [TAU_ELEMS] dense
{
    const int bid = blockIdx.x;
    if (bid < WORKER_NUM / 4) {
        // 4 waves per block, 1 worker per wave
        const int gtid = bid * 256 + (int)threadIdx.x;
        const int w    = gtid >> 6;          // worker index 0..1999
        const int lane = threadIdx.x & 63;
        float v = inputs[w * INPUT_DIM + lane] * W[lane];
        // 64-lane butterfly sum
        #pragma unroll
        for (int m = 32; m > 0; m >>= 1) v += __shfl_xor(v, m, 64);
        if (lane == 0) {
            float z  = v + b[0];
            float p1 = 1.0f / (1.0f + expf(-z));
            float p2 = (1.0f - p1) / (float)(EDGE_TYPE - 1);
            float l1 = log2f(p1);
            float l2 = log2f(p2);
            params[w] = make_float2(l2, l1 - l2);
        }
    } else {
        const int j = (bid - WORKER_NUM / 4) * 256 + (int)threadIdx.x;
        if (j < TAU_ELEMS) {
            const int t = j / EDGE_TYPE;
            const int e = j - t * EDGE_TYPE;
            tau[j] = inputs[(WORKER_NUM + t) * INPUT_DIM + e];
        }
    }
}

// ---------------------------------------------------------------------------
// Main: out[w][t][e] = exp2(base[w] + tau[t*10+e] * slope[w])
// Grid-stride over float4s. 50,000 % 4 == 0 so each float4 stays in one w.
// ---------------------------------------------------------------------------
__global__ __launch_bounds__(256) void decoder_kernel(
    const float2* __restrict__ params,
    const float4* __restrict__ tau4,
    float4* __restrict__ out4)
{
    const int stride = (int)(gridDim.x * blockDim.x);
    const int total4 = TOTAL4;
    for (int i4 = (int)(blockIdx.x * blockDim.x + threadIdx.x);
         i4 < total4; i4 += stride) {
        const int w  = i4 / TAU4;            // magic-mul division
        const int r4 = i4 - w * TAU4;
        const float2 pw = params[w];         // wave-uniform -> broadcast
        const float4 tv = tau4[r4];          // L2-resident (200 KB)
        float4 o;
        o.x = exp2f(fmaf(tv.x, pw.y, pw.x));
        o.y = exp2f(fmaf(tv.y, pw.y, pw.x));
        o.z = exp2f(fmaf(tv.z, pw.y, pw.x));
        o.w = exp2f(fmaf(tv.w, pw.y, pw.x));
        out4[i4] = o;
    }
}

extern "C" void kernel_launch(void* const* d_in, const int* in_sizes, int n_in,
                              void* d_out, int out_size, void* d_ws, size_t ws_size,
                              hipStream_t stream) {
    const float* inputs = (const float*)d_in[0];
    const float* W      = (const float*)d_in[1];
    const float* b      = (const float*)d_in[2];
    float* out          = (float*)d_out;

    // Workspace layout: params (2000 float2, 16 KB slot) | tau (50,000 float)
    float2* params = (float2*)d_ws;
    float*  tau    = (float*)((char*)d_ws + 16384);

    const int prep_blocks = WORKER_NUM / 4 + (TAU_ELEMS + 255) / 256; // 500 + 196
    prep_kernel<<<prep_blocks, 256, 0, stream>>>(inputs, W, b, params, tau);

    decoder_kernel<<<2048, 256, 0, stream>>>(params, (const float4*)tau,
                                             (float4*)out);
}